// Round 2
// baseline (227.080 us; speedup 1.0000x reference)
//
#include <hip/hip_runtime.h>

#define CCH 128
#define SV 24
#define NVOX 13824   // 24^3

typedef unsigned short u16;
typedef unsigned int   u32;

__device__ __forceinline__ float bf2f(u16 u) {
    return __uint_as_float(((u32)u) << 16);
}
__device__ __forceinline__ u16 f2bf(float f) {
    u32 x = __float_as_uint(f);
    u32 r = x + 0x7fffu + ((x >> 16) & 1u);   // round-to-nearest-even
    return (u16)(r >> 16);
}

// Load 4 consecutive elements as fp32, from either a float* or bf16* buffer.
template<bool FP32>
__device__ __forceinline__ void ld4(const void* base, size_t idx, float* f) {
    if (FP32) {
        const float4 t = *(const float4*)((const float*)base + idx);
        f[0] = t.x; f[1] = t.y; f[2] = t.z; f[3] = t.w;
    } else {
        const ushort4 t = *(const ushort4*)((const u16*)base + idx);
        f[0] = bf2f(t.x); f[1] = bf2f(t.y); f[2] = bf2f(t.z); f[3] = bf2f(t.w);
    }
}
template<bool FP32>
__device__ __forceinline__ float ld1(const void* base, size_t idx) {
    return FP32 ? ((const float*)base)[idx] : bf2f(((const u16*)base)[idx]);
}

// ---------------------------------------------------------------------------
// dtype sniffer: bf16 N(0,1) data has every u16 exponent in [90,160] (or 0);
// fp32 data read as u16 has random low-halves -> ~half fail. flag=1 => fp32.
// ---------------------------------------------------------------------------
__global__ void detect_kernel(const u16* __restrict__ x, int* __restrict__ flag) {
    if (threadIdx.x == 0 && blockIdx.x == 0) {
        int cnt = 0;
        for (int i = 0; i < 128; ++i) {
            const u16 v = x[i];
            const int e = (v >> 7) & 0xFF;
            if (e == 0 || (e >= 90 && e <= 160)) ++cnt;
        }
        *flag = (cnt >= 120) ? 0 : 1;
    }
}

// ---------------------------------------------------------------------------
// QKV: per-voxel 128x128 matvec x3. q -> d_out (same dtype as output),
// k/v -> ws fp32 [vox][c] + pad row (=bias) at vox==NVOX + 27-entry bias vec.
// 256 thr: 32 o-groups x 8 vox-groups, 4x4 tile each. Grid NVOX/32 = 432.
// ---------------------------------------------------------------------------
template<bool FP32>
__device__ __forceinline__ void qkv_body(
    const void* __restrict__ x,
    const void* __restrict__ wq, const void* __restrict__ bq,
    const void* __restrict__ wk, const void* __restrict__ bk,
    const void* __restrict__ wv, const void* __restrict__ bv,
    const void* __restrict__ relh, const void* __restrict__ relw,
    const void* __restrict__ reld,
    void* __restrict__ qout, float* __restrict__ kws, float* __restrict__ vws,
    float* __restrict__ biasW)
{
    const int tid = threadIdx.x;
    const int o0  = (tid & 31) * 4;
    const int vx0 = blockIdx.x * 32 + (tid >> 5) * 4;

    float accq[4][4] = {{0.f}}, acck[4][4] = {{0.f}}, accv[4][4] = {{0.f}};

    for (int c4 = 0; c4 < CCH; c4 += 4) {
        float xf[4][4];
#pragma unroll
        for (int cc = 0; cc < 4; ++cc)
            ld4<FP32>(x, (size_t)(c4 + cc) * NVOX + vx0, xf[cc]);

        float wqf[4][4], wkf[4][4], wvf[4][4];
#pragma unroll
        for (int oo = 0; oo < 4; ++oo) {
            const size_t wo = (size_t)(o0 + oo) * CCH + c4;
            ld4<FP32>(wq, wo, wqf[oo]);
            ld4<FP32>(wk, wo, wkf[oo]);
            ld4<FP32>(wv, wo, wvf[oo]);
        }
#pragma unroll
        for (int cc = 0; cc < 4; ++cc) {
#pragma unroll
            for (int oo = 0; oo < 4; ++oo) {
                const float a = wqf[oo][cc], b = wkf[oo][cc], c = wvf[oo][cc];
#pragma unroll
                for (int vv = 0; vv < 4; ++vv) {
                    const float xv = xf[cc][vv];
                    accq[vv][oo] = fmaf(a, xv, accq[vv][oo]);
                    acck[vv][oo] = fmaf(b, xv, acck[vv][oo]);
                    accv[vv][oo] = fmaf(c, xv, accv[vv][oo]);
                }
            }
        }
    }

    float bqf[4], bkf[4], bvf[4];
    ld4<FP32>(bq, o0, bqf);
    ld4<FP32>(bk, o0, bkf);
    ld4<FP32>(bv, o0, bvf);

#pragma unroll
    for (int vv = 0; vv < 4; ++vv) {
        const size_t row = (size_t)(vx0 + vv) * CCH + o0;
        const float q0 = accq[vv][0] + bqf[0], q1 = accq[vv][1] + bqf[1];
        const float q2 = accq[vv][2] + bqf[2], q3 = accq[vv][3] + bqf[3];
        if (FP32) {
            float4 sq = {q0, q1, q2, q3};
            *(float4*)((float*)qout + row) = sq;
        } else {
            ushort4 sq = {f2bf(q0), f2bf(q1), f2bf(q2), f2bf(q3)};
            *(ushort4*)((u16*)qout + row) = sq;
        }
        float4 sk = {acck[vv][0] + bkf[0], acck[vv][1] + bkf[1],
                     acck[vv][2] + bkf[2], acck[vv][3] + bkf[3]};
        float4 sv = {accv[vv][0] + bvf[0], accv[vv][1] + bvf[1],
                     accv[vv][2] + bvf[2], accv[vv][3] + bvf[3]};
        *(float4*)(kws + row) = sk;
        *(float4*)(vws + row) = sv;
    }

    if (blockIdx.x == 0) {
        if (tid < CCH) {
            kws[(size_t)NVOX * CCH + tid] = ld1<FP32>(bk, tid);
            vws[(size_t)NVOX * CCH + tid] = ld1<FP32>(bv, tid);
        }
        if (tid < 27) {
            const int i = tid / 9, j = (tid / 3) % 3, l = tid % 3;
            float s = 0.f;
            for (int c = 0; c < 64; ++c)
                s += ld1<FP32>(relh, c * 3 + i) + ld1<FP32>(relw, c * 3 + j) +
                     ld1<FP32>(reld, c * 3 + l);
            biasW[tid] = s;
        }
    }
}

__global__ __launch_bounds__(256) void qkv_kernel(
    const void* x, const void* wq, const void* bq, const void* wk,
    const void* bk, const void* wv, const void* bv,
    const void* relh, const void* relw, const void* reld,
    void* qout, float* kws, float* vws, float* biasW,
    const int* __restrict__ flag)
{
    if (*flag)
        qkv_body<true>(x, wq, bq, wk, bk, wv, bv, relh, relw, reld,
                       qout, kws, vws, biasW);
    else
        qkv_body<false>(x, wq, bq, wk, bk, wv, bv, relh, relw, reld,
                        qout, kws, vws, biasW);
}

// ---------------------------------------------------------------------------
// Attention: 16 lanes/voxel (8 ch each), 16 voxels per 256-thr block.
// q read from qout (== d_out), overwritten with the result (same addresses,
// read-before-write within the same thread). Grid NVOX/16 = 864.
// ---------------------------------------------------------------------------
template<bool FP32>
__device__ __forceinline__ void attn_body(
    void* __restrict__ qo, const float* __restrict__ kws,
    const float* __restrict__ vws, const float* __restrict__ biasW)
{
    const int tid  = threadIdx.x;
    const int lane = tid & 15;
    const int vox  = blockIdx.x * 16 + (tid >> 4);
    const int h    = vox / 576;
    const int rem  = vox - h * 576;
    const int w    = rem / 24;
    const int d    = rem - w * 24;
    const int ch   = lane * 8;

    float q[8];
    ld4<FP32>(qo, (size_t)vox * CCH + ch, q);
    ld4<FP32>(qo, (size_t)vox * CCH + ch + 4, q + 4);

    float qs = q[0] + q[1] + q[2] + q[3] + q[4] + q[5] + q[6] + q[7];
#pragma unroll
    for (int m = 1; m < 16; m <<= 1) qs += __shfl_xor(qs, m, 64);

    float bw[27];
#pragma unroll
    for (int s = 0; s < 27; ++s) bw[s] = biasW[s];

    int   offs[27];
    float ps[27];
#pragma unroll
    for (int s = 0; s < 27; ++s) {
        const int nh = h + s / 9 - 1;
        const int nw = w + (s / 3) % 3 - 1;
        const int nd = d + s % 3 - 1;
        const bool ok = ((unsigned)nh < (unsigned)SV) &&
                        ((unsigned)nw < (unsigned)SV) &&
                        ((unsigned)nd < (unsigned)SV);
        const int idx = ok ? ((nh * SV + nw) * SV + nd) : NVOX;
        offs[s] = idx * CCH + ch;
        const float* kr = kws + offs[s];
        const float4 k0 = *(const float4*)kr;
        const float4 k1 = *(const float4*)(kr + 4);
        ps[s] = q[0] * k0.x + q[1] * k0.y + q[2] * k0.z + q[3] * k0.w +
                q[4] * k1.x + q[5] * k1.y + q[6] * k1.z + q[7] * k1.w;
    }

#pragma unroll
    for (int m = 1; m < 16; m <<= 1) {
#pragma unroll
        for (int s = 0; s < 27; ++s) ps[s] += __shfl_xor(ps[s], m, 64);
    }

#pragma unroll
    for (int s = 0; s < 27; ++s) ps[s] = fmaf(qs, bw[s], ps[s]);

    float mx = ps[0];
#pragma unroll
    for (int s = 1; s < 27; ++s) mx = fmaxf(mx, ps[s]);
    float sum = 0.f;
#pragma unroll
    for (int s = 0; s < 27; ++s) { ps[s] = __expf(ps[s] - mx); sum += ps[s]; }
    const float inv = 1.f / sum;

    float o[8] = {0.f, 0.f, 0.f, 0.f, 0.f, 0.f, 0.f, 0.f};
#pragma unroll
    for (int s = 0; s < 27; ++s) {
        const float a = ps[s] * inv;
        const float* vr = vws + offs[s];
        const float4 v0 = *(const float4*)vr;
        const float4 v1 = *(const float4*)(vr + 4);
        o[0] = fmaf(a, v0.x, o[0]); o[1] = fmaf(a, v0.y, o[1]);
        o[2] = fmaf(a, v0.z, o[2]); o[3] = fmaf(a, v0.w, o[3]);
        o[4] = fmaf(a, v1.x, o[4]); o[5] = fmaf(a, v1.y, o[5]);
        o[6] = fmaf(a, v1.z, o[6]); o[7] = fmaf(a, v1.w, o[7]);
    }

    if (FP32) {
        float* dst = (float*)qo + (size_t)vox * CCH + ch;
        float4 s0 = {o[0], o[1], o[2], o[3]};
        float4 s1 = {o[4], o[5], o[6], o[7]};
        *(float4*)dst = s0;
        *(float4*)(dst + 4) = s1;
    } else {
        u16* dst = (u16*)qo + (size_t)vox * CCH + ch;
        uint4 st;
        st.x = (u32)f2bf(o[0]) | ((u32)f2bf(o[1]) << 16);
        st.y = (u32)f2bf(o[2]) | ((u32)f2bf(o[3]) << 16);
        st.z = (u32)f2bf(o[4]) | ((u32)f2bf(o[5]) << 16);
        st.w = (u32)f2bf(o[6]) | ((u32)f2bf(o[7]) << 16);
        *(uint4*)dst = st;
    }
}

__global__ __launch_bounds__(256) void attn_kernel(
    void* qo, const float* kws, const float* vws, const float* biasW,
    const int* __restrict__ flag)
{
    if (*flag) attn_body<true>(qo, kws, vws, biasW);
    else       attn_body<false>(qo, kws, vws, biasW);
}

// ---------------------------------------------------------------------------
extern "C" void kernel_launch(void* const* d_in, const int* in_sizes, int n_in,
                              void* d_out, int out_size, void* d_ws,
                              size_t ws_size, hipStream_t stream)
{
    const void* x    = d_in[0];
    const void* wq   = d_in[1];
    const void* bq   = d_in[2];
    const void* wk   = d_in[3];
    const void* bk   = d_in[4];
    const void* wv   = d_in[5];
    const void* bv   = d_in[6];
    const void* relh = d_in[7];
    const void* relw = d_in[8];
    const void* reld = d_in[9];

    float* kws   = (float*)d_ws;                       // (NVOX+1)*128
    float* vws   = kws + (size_t)(NVOX + 1) * CCH;     // (NVOX+1)*128
    float* biasW = vws + (size_t)(NVOX + 1) * CCH;     // 27
    int*   flag  = (int*)(biasW + 27);                 // 1

    detect_kernel<<<1, 64, 0, stream>>>((const u16*)x, flag);
    qkv_kernel<<<NVOX / 32, 256, 0, stream>>>(x, wq, bq, wk, bk, wv, bv,
                                              relh, relw, reld,
                                              d_out, kws, vws, biasW, flag);
    attn_kernel<<<NVOX / 16, 256, 0, stream>>>(d_out, kws, vws, biasW, flag);
}

// Round 4
// 216.980 us; speedup vs baseline: 1.0465x; 1.0465x over previous
//
#include <hip/hip_runtime.h>

#define CCH 128
#define SV 24
#define NVOX 13824   // 24^3

// ---------------------------------------------------------------------------
// Projection kernel: one of {q,k,v} per blockIdx.y (wave-uniform select).
// Per-voxel 128x128 matvec, all fp32. Block: 256 thr = 32 o-groups x 8
// vox-groups, thread tile 4o x 4vox. Grid: (432, 3).
// q -> d_out, k/v -> ws with pad row (= bias) at vox==NVOX.
// Also: m==1 block 0 computes the 27-entry window bias vector.
// ---------------------------------------------------------------------------
__global__ __launch_bounds__(256) void proj_kernel(
    const float* __restrict__ x,
    const float* __restrict__ wq, const float* __restrict__ bq,
    const float* __restrict__ wk, const float* __restrict__ bk,
    const float* __restrict__ wv, const float* __restrict__ bv,
    const float* __restrict__ relh, const float* __restrict__ relw,
    const float* __restrict__ reld,
    float* __restrict__ qout, float* __restrict__ kws, float* __restrict__ vws,
    float* __restrict__ biasW)
{
    const int m = blockIdx.y;                  // 0=q 1=k 2=v
    const float* __restrict__ w = (m == 0) ? wq : (m == 1) ? wk : wv;
    const float* __restrict__ b = (m == 0) ? bq : (m == 1) ? bk : bv;
    float* __restrict__ out     = (m == 0) ? qout : (m == 1) ? kws : vws;

    const int tid = threadIdx.x;
    const int o0  = (tid & 31) * 4;
    const int vx0 = blockIdx.x * 32 + (tid >> 5) * 4;

    float acc[4][4] = {{0.f}};                 // [vox][o]

    for (int c4 = 0; c4 < CCH; c4 += 4) {
        float4 xf[4];
#pragma unroll
        for (int cc = 0; cc < 4; ++cc)
            xf[cc] = *(const float4*)(x + (size_t)(c4 + cc) * NVOX + vx0);

        float4 wf[4];
#pragma unroll
        for (int oo = 0; oo < 4; ++oo)
            wf[oo] = *(const float4*)(w + (size_t)(o0 + oo) * CCH + c4);

#pragma unroll
        for (int oo = 0; oo < 4; ++oo) {
            acc[0][oo] = fmaf(wf[oo].x, xf[0].x, acc[0][oo]);
            acc[1][oo] = fmaf(wf[oo].x, xf[0].y, acc[1][oo]);
            acc[2][oo] = fmaf(wf[oo].x, xf[0].z, acc[2][oo]);
            acc[3][oo] = fmaf(wf[oo].x, xf[0].w, acc[3][oo]);
            acc[0][oo] = fmaf(wf[oo].y, xf[1].x, acc[0][oo]);
            acc[1][oo] = fmaf(wf[oo].y, xf[1].y, acc[1][oo]);
            acc[2][oo] = fmaf(wf[oo].y, xf[1].z, acc[2][oo]);
            acc[3][oo] = fmaf(wf[oo].y, xf[1].w, acc[3][oo]);
            acc[0][oo] = fmaf(wf[oo].z, xf[2].x, acc[0][oo]);
            acc[1][oo] = fmaf(wf[oo].z, xf[2].y, acc[1][oo]);
            acc[2][oo] = fmaf(wf[oo].z, xf[2].z, acc[2][oo]);
            acc[3][oo] = fmaf(wf[oo].z, xf[2].w, acc[3][oo]);
            acc[0][oo] = fmaf(wf[oo].w, xf[3].x, acc[0][oo]);
            acc[1][oo] = fmaf(wf[oo].w, xf[3].y, acc[1][oo]);
            acc[2][oo] = fmaf(wf[oo].w, xf[3].z, acc[2][oo]);
            acc[3][oo] = fmaf(wf[oo].w, xf[3].w, acc[3][oo]);
        }
    }

    const float4 bf = *(const float4*)(b + o0);

#pragma unroll
    for (int vv = 0; vv < 4; ++vv) {
        const size_t row = (size_t)(vx0 + vv) * CCH + o0;
        float4 st = {acc[vv][0] + bf.x, acc[vv][1] + bf.y,
                     acc[vv][2] + bf.z, acc[vv][3] + bf.w};
        *(float4*)(out + row) = st;
    }

    if (blockIdx.x == 0) {
        if (m == 1 && tid < CCH) kws[(size_t)NVOX * CCH + tid] = bk[tid];
        if (m == 2 && tid < CCH) vws[(size_t)NVOX * CCH + tid] = bv[tid];
        if (m == 1 && tid < 27) {
            const int i = tid / 9, j = (tid / 3) % 3, l = tid % 3;
            float s = 0.f;
            for (int c = 0; c < 64; ++c)
                s += relh[c * 3 + i] + relw[c * 3 + j] + reld[c * 3 + l];
            biasW[tid] = s;
        }
    }
}

// ---------------------------------------------------------------------------
// Attention: 16 lanes/voxel (8 ch each), 16 voxels per 256-thr block.
// q read from d_out (fp32) and overwritten with the result in-place
// (each thread reads/writes only its own addresses; no cross-thread use of q
// after the qk phase... q is only ever the block's own voxel rows).
// Out-of-range neighbors -> pad row at vox==NVOX (k=bk, v=bv).
// Grid: NVOX/16 = 864.
// ---------------------------------------------------------------------------
__global__ __launch_bounds__(256) void attn_kernel(
    float* __restrict__ qo, const float* __restrict__ kws,
    const float* __restrict__ vws, const float* __restrict__ biasW)
{
    const int tid  = threadIdx.x;
    const int lane = tid & 15;
    const int vox  = blockIdx.x * 16 + (tid >> 4);
    const int h    = vox / 576;
    const int rem  = vox - h * 576;
    const int w    = rem / 24;
    const int d    = rem - w * 24;
    const int ch   = lane * 8;

    const float* qrow = qo + (size_t)vox * CCH + ch;
    const float4 q0 = *(const float4*)qrow;
    const float4 q1 = *(const float4*)(qrow + 4);

    float qs = q0.x + q0.y + q0.z + q0.w + q1.x + q1.y + q1.z + q1.w;
#pragma unroll
    for (int mm = 1; mm < 16; mm <<= 1) qs += __shfl_xor(qs, mm, 64);

    int   offs[27];
    float ps[27];
#pragma unroll
    for (int s = 0; s < 27; ++s) {
        const int nh = h + s / 9 - 1;
        const int nw = w + (s / 3) % 3 - 1;
        const int nd = d + s % 3 - 1;
        const bool ok = ((unsigned)nh < (unsigned)SV) &&
                        ((unsigned)nw < (unsigned)SV) &&
                        ((unsigned)nd < (unsigned)SV);
        const int idx = ok ? ((nh * SV + nw) * SV + nd) : NVOX;
        offs[s] = idx * CCH + ch;
        const float* kr = kws + offs[s];
        const float4 k0 = *(const float4*)kr;
        const float4 k1 = *(const float4*)(kr + 4);
        float p = q0.x * k0.x;
        p = fmaf(q0.y, k0.y, p); p = fmaf(q0.z, k0.z, p);
        p = fmaf(q0.w, k0.w, p); p = fmaf(q1.x, k1.x, p);
        p = fmaf(q1.y, k1.y, p); p = fmaf(q1.z, k1.z, p);
        p = fmaf(q1.w, k1.w, p);
        ps[s] = p;
    }

#pragma unroll
    for (int mm = 1; mm < 16; mm <<= 1) {
#pragma unroll
        for (int s = 0; s < 27; ++s) ps[s] += __shfl_xor(ps[s], mm, 64);
    }

#pragma unroll
    for (int s = 0; s < 27; ++s) ps[s] = fmaf(qs, biasW[s], ps[s]);

    float mx = ps[0];
#pragma unroll
    for (int s = 1; s < 27; ++s) mx = fmaxf(mx, ps[s]);
    float sum = 0.f;
#pragma unroll
    for (int s = 0; s < 27; ++s) { ps[s] = __expf(ps[s] - mx); sum += ps[s]; }
    const float inv = 1.f / sum;

    float o[8] = {0.f, 0.f, 0.f, 0.f, 0.f, 0.f, 0.f, 0.f};
#pragma unroll
    for (int s = 0; s < 27; ++s) {
        const float a = ps[s] * inv;
        const float* vr = vws + offs[s];
        const float4 v0 = *(const float4*)vr;
        const float4 v1 = *(const float4*)(vr + 4);
        o[0] = fmaf(a, v0.x, o[0]); o[1] = fmaf(a, v0.y, o[1]);
        o[2] = fmaf(a, v0.z, o[2]); o[3] = fmaf(a, v0.w, o[3]);
        o[4] = fmaf(a, v1.x, o[4]); o[5] = fmaf(a, v1.y, o[5]);
        o[6] = fmaf(a, v1.z, o[6]); o[7] = fmaf(a, v1.w, o[7]);
    }

    float* dst = qo + (size_t)vox * CCH + ch;
    float4 s0 = {o[0], o[1], o[2], o[3]};
    float4 s1 = {o[4], o[5], o[6], o[7]};
    *(float4*)dst = s0;
    *(float4*)(dst + 4) = s1;
}

// ---------------------------------------------------------------------------
extern "C" void kernel_launch(void* const* d_in, const int* in_sizes, int n_in,
                              void* d_out, int out_size, void* d_ws,
                              size_t ws_size, hipStream_t stream)
{
    const float* x    = (const float*)d_in[0];
    const float* wq   = (const float*)d_in[1];
    const float* bq   = (const float*)d_in[2];
    const float* wk   = (const float*)d_in[3];
    const float* bk   = (const float*)d_in[4];
    const float* wv   = (const float*)d_in[5];
    const float* bv   = (const float*)d_in[6];
    const float* relh = (const float*)d_in[7];
    const float* relw = (const float*)d_in[8];
    const float* reld = (const float*)d_in[9];

    float* kws   = (float*)d_ws;                       // (NVOX+1)*128 fp32
    float* vws   = kws + (size_t)(NVOX + 1) * CCH;     // (NVOX+1)*128 fp32
    float* biasW = vws + (size_t)(NVOX + 1) * CCH;     // 27 fp32

    dim3 pgrid(NVOX / 32, 3);
    proj_kernel<<<pgrid, 256, 0, stream>>>(x, wq, bq, wk, bk, wv, bv,
                                           relh, relw, reld,
                                           (float*)d_out, kws, vws, biasW);
    attn_kernel<<<NVOX / 16, 256, 0, stream>>>((float*)d_out, kws, vws, biasW);
}

// Round 5
// 109.263 us; speedup vs baseline: 2.0783x; 1.9859x over previous
//
#include <hip/hip_runtime.h>

#define CCH 128
#define SV 24
#define NVOX 13824   // 24^3

typedef unsigned short u16;
typedef unsigned int   u32;

__device__ __forceinline__ u16 f2bf(float f) {
    u32 x = __float_as_uint(f);
    u32 r = x + 0x7fffu + ((x >> 16) & 1u);   // round-to-nearest-even
    return (u16)(r >> 16);
}
// unpack uint4 (8 packed bf16) -> 8 floats (elem i at u16 index i, LE)
__device__ __forceinline__ void cvt8(uint4 r, float* f) {
    f[0] = __uint_as_float(r.x << 16); f[1] = __uint_as_float(r.x & 0xffff0000u);
    f[2] = __uint_as_float(r.y << 16); f[3] = __uint_as_float(r.y & 0xffff0000u);
    f[4] = __uint_as_float(r.z << 16); f[5] = __uint_as_float(r.z & 0xffff0000u);
    f[6] = __uint_as_float(r.w << 16); f[7] = __uint_as_float(r.w & 0xffff0000u);
}

// ---------------------------------------------------------------------------
// Projection GEMM: C[vox][o] = sum_c X[c][vox] * W[o][c] + b[o].
// One m in {q,k,v} per blockIdx.y. Block = 64 vox x 128 o, K-tile 32.
// LDS: Xs[k][vox] 8 KB + Ws[k][o] 16 KB (transposed store -> b128 compute
// reads, conflict-free). Thread tile 4 vox x 8 o.
// q -> d_out fp32; k/v -> ws as packed bf16 rows + pad row at vox==NVOX.
// Grid (216, 3).
// ---------------------------------------------------------------------------
__global__ __launch_bounds__(256) void proj_kernel(
    const float* __restrict__ x,
    const float* __restrict__ wq, const float* __restrict__ bq,
    const float* __restrict__ wk, const float* __restrict__ bk,
    const float* __restrict__ wv, const float* __restrict__ bv,
    const float* __restrict__ relh, const float* __restrict__ relw,
    const float* __restrict__ reld,
    float* __restrict__ qout, u16* __restrict__ kws, u16* __restrict__ vws,
    float* __restrict__ biasW)
{
    const int m = blockIdx.y;                  // 0=q 1=k 2=v
    const float* __restrict__ w = (m == 0) ? wq : (m == 1) ? wk : wv;
    const float* __restrict__ b = (m == 0) ? bq : (m == 1) ? bk : bv;

    __shared__ float Xs[32][64];
    __shared__ float Ws[32][128];

    const int tid  = threadIdx.x;
    const int vox0 = blockIdx.x * 64;
    const int v0   = (tid & 15) * 4;           // compute: voxel group
    const int o0   = (tid >> 4) * 8;           // compute: output group

    // staging indices
    const int xc  = tid >> 3;                  // 0..31  (c-row)
    const int xv  = (tid & 7) * 4;             // 0,4,..,28
    const int wo  = tid >> 1;                  // 0..127 (o-row)
    const int wkh = (tid & 1) * 16;            // 0 or 16

    float acc[4][8] = {{0.f}};

    for (int k0 = 0; k0 < CCH; k0 += 32) {
        // X slice: 32 c-rows x 64 vox, coalesced (8 lanes cover 256B row)
        {
            const float* src = x + (size_t)(k0 + xc) * NVOX + vox0 + xv;
            const float4 a0 = *(const float4*)src;
            const float4 a1 = *(const float4*)(src + 32);
            *(float4*)&Xs[xc][xv]      = a0;
            *(float4*)&Xs[xc][xv + 32] = a1;
        }
        // W slice: rows [o][k0+kh .. +15] -> transposed Ws[k][o]
        {
            const float* src = w + (size_t)wo * CCH + k0 + wkh;
            const float4 b0 = *(const float4*)src;
            const float4 b1 = *(const float4*)(src + 4);
            const float4 b2 = *(const float4*)(src + 8);
            const float4 b3 = *(const float4*)(src + 12);
            Ws[wkh + 0][wo] = b0.x;  Ws[wkh + 1][wo] = b0.y;
            Ws[wkh + 2][wo] = b0.z;  Ws[wkh + 3][wo] = b0.w;
            Ws[wkh + 4][wo] = b1.x;  Ws[wkh + 5][wo] = b1.y;
            Ws[wkh + 6][wo] = b1.z;  Ws[wkh + 7][wo] = b1.w;
            Ws[wkh + 8][wo] = b2.x;  Ws[wkh + 9][wo] = b2.y;
            Ws[wkh + 10][wo] = b2.z; Ws[wkh + 11][wo] = b2.w;
            Ws[wkh + 12][wo] = b3.x; Ws[wkh + 13][wo] = b3.y;
            Ws[wkh + 14][wo] = b3.z; Ws[wkh + 15][wo] = b3.w;
        }
        __syncthreads();

#pragma unroll
        for (int k = 0; k < 32; ++k) {
            const float4 xf = *(const float4*)&Xs[k][v0];
            const float4 w0 = *(const float4*)&Ws[k][o0];
            const float4 w1 = *(const float4*)&Ws[k][o0 + 4];
            const float xr[4] = {xf.x, xf.y, xf.z, xf.w};
            const float wr[8] = {w0.x, w0.y, w0.z, w0.w,
                                 w1.x, w1.y, w1.z, w1.w};
#pragma unroll
            for (int vv = 0; vv < 4; ++vv)
#pragma unroll
                for (int oo = 0; oo < 8; ++oo)
                    acc[vv][oo] = fmaf(xr[vv], wr[oo], acc[vv][oo]);
        }
        __syncthreads();
    }

    const float4 bf0 = *(const float4*)(b + o0);
    const float4 bf1 = *(const float4*)(b + o0 + 4);
    const float br[8] = {bf0.x, bf0.y, bf0.z, bf0.w,
                         bf1.x, bf1.y, bf1.z, bf1.w};

#pragma unroll
    for (int vv = 0; vv < 4; ++vv) {
        float r[8];
#pragma unroll
        for (int oo = 0; oo < 8; ++oo) r[oo] = acc[vv][oo] + br[oo];
        const size_t row = (size_t)(vox0 + v0 + vv) * CCH + o0;
        if (m == 0) {
            float4 s0 = {r[0], r[1], r[2], r[3]};
            float4 s1 = {r[4], r[5], r[6], r[7]};
            *(float4*)(qout + row) = s0;
            *(float4*)(qout + row + 4) = s1;
        } else {
            u16* out = (m == 1) ? kws : vws;
            uint4 st;
            st.x = (u32)f2bf(r[0]) | ((u32)f2bf(r[1]) << 16);
            st.y = (u32)f2bf(r[2]) | ((u32)f2bf(r[3]) << 16);
            st.z = (u32)f2bf(r[4]) | ((u32)f2bf(r[5]) << 16);
            st.w = (u32)f2bf(r[6]) | ((u32)f2bf(r[7]) << 16);
            *(uint4*)(out + row) = st;
        }
    }

    if (blockIdx.x == 0) {
        if (m == 1 && tid < CCH) kws[(size_t)NVOX * CCH + tid] = f2bf(bk[tid]);
        if (m == 2 && tid < CCH) vws[(size_t)NVOX * CCH + tid] = f2bf(bv[tid]);
        if (m == 1 && tid < 27) {
            const int i = tid / 9, j = (tid / 3) % 3, l = tid % 3;
            float s = 0.f;
            for (int c = 0; c < 64; ++c)
                s += relh[c * 3 + i] + relw[c * 3 + j] + reld[c * 3 + l];
            biasW[tid] = s;
        }
    }
}

// ---------------------------------------------------------------------------
// neighbor row offset for window slot s (compile-time s after unroll)
// ---------------------------------------------------------------------------
__device__ __forceinline__ int nbr_off(int h, int w, int d, int s, int ch) {
    const int nh = h + s / 9 - 1;
    const int nw = w + (s / 3) % 3 - 1;
    const int nd = d + s % 3 - 1;
    const bool ok = ((unsigned)nh < (unsigned)SV) &&
                    ((unsigned)nw < (unsigned)SV) &&
                    ((unsigned)nd < (unsigned)SV);
    const int idx = ok ? ((nh * SV + nw) * SV + nd) : NVOX;
    return idx * CCH + ch;
}

// ---------------------------------------------------------------------------
// Attention: 16 lanes/voxel (8 ch each), 16 voxels per 256-thr block.
// q fp32 from d_out (overwritten in place); k/v bf16 gathers from ws in
// explicit batches of 9 uint4 loads for latency overlap. Grid 864.
// ---------------------------------------------------------------------------
__global__ __launch_bounds__(256) void attn_kernel(
    float* __restrict__ qo, const u16* __restrict__ kws,
    const u16* __restrict__ vws, const float* __restrict__ biasW)
{
    const int tid  = threadIdx.x;
    const int lane = tid & 15;
    const int vox  = blockIdx.x * 16 + (tid >> 4);
    const int h    = vox / 576;
    const int rem  = vox - h * 576;
    const int w    = rem / 24;
    const int d    = rem - w * 24;
    const int ch   = lane * 8;

    const float* qrow = qo + (size_t)vox * CCH + ch;
    const float4 q0 = *(const float4*)qrow;
    const float4 q1 = *(const float4*)(qrow + 4);
    const float qr[8] = {q0.x, q0.y, q0.z, q0.w, q1.x, q1.y, q1.z, q1.w};

    float qs = qr[0] + qr[1] + qr[2] + qr[3] + qr[4] + qr[5] + qr[6] + qr[7];
#pragma unroll
    for (int mm = 1; mm < 16; mm <<= 1) qs += __shfl_xor(qs, mm, 64);

    float ps[27];
    // ---- QK phase: 3 batches of 9 rows ----
#pragma unroll
    for (int sb = 0; sb < 27; sb += 9) {
        uint4 kf[9];
#pragma unroll
        for (int j = 0; j < 9; ++j)
            kf[j] = *(const uint4*)(kws + nbr_off(h, w, d, sb + j, ch));
#pragma unroll
        for (int j = 0; j < 9; ++j) {
            float f[8];
            cvt8(kf[j], f);
            float p = qr[0] * f[0];
            p = fmaf(qr[1], f[1], p); p = fmaf(qr[2], f[2], p);
            p = fmaf(qr[3], f[3], p); p = fmaf(qr[4], f[4], p);
            p = fmaf(qr[5], f[5], p); p = fmaf(qr[6], f[6], p);
            p = fmaf(qr[7], f[7], p);
            ps[sb + j] = p;
        }
    }

#pragma unroll
    for (int mm = 1; mm < 16; mm <<= 1) {
#pragma unroll
        for (int s = 0; s < 27; ++s) ps[s] += __shfl_xor(ps[s], mm, 64);
    }

#pragma unroll
    for (int s = 0; s < 27; ++s) ps[s] = fmaf(qs, biasW[s], ps[s]);

    float mx = ps[0];
#pragma unroll
    for (int s = 1; s < 27; ++s) mx = fmaxf(mx, ps[s]);
    float sum = 0.f;
#pragma unroll
    for (int s = 0; s < 27; ++s) { ps[s] = __expf(ps[s] - mx); sum += ps[s]; }
    const float inv = 1.f / sum;
#pragma unroll
    for (int s = 0; s < 27; ++s) ps[s] *= inv;

    // ---- PV phase: 3 batches of 9 rows ----
    float o[8] = {0.f, 0.f, 0.f, 0.f, 0.f, 0.f, 0.f, 0.f};
#pragma unroll
    for (int sb = 0; sb < 27; sb += 9) {
        uint4 vf[9];
#pragma unroll
        for (int j = 0; j < 9; ++j)
            vf[j] = *(const uint4*)(vws + nbr_off(h, w, d, sb + j, ch));
#pragma unroll
        for (int j = 0; j < 9; ++j) {
            float f[8];
            cvt8(vf[j], f);
            const float a = ps[sb + j];
#pragma unroll
            for (int e = 0; e < 8; ++e) o[e] = fmaf(a, f[e], o[e]);
        }
    }

    float* dst = qo + (size_t)vox * CCH + ch;
    float4 s0 = {o[0], o[1], o[2], o[3]};
    float4 s1 = {o[4], o[5], o[6], o[7]};
    *(float4*)dst = s0;
    *(float4*)(dst + 4) = s1;
}

// ---------------------------------------------------------------------------
extern "C" void kernel_launch(void* const* d_in, const int* in_sizes, int n_in,
                              void* d_out, int out_size, void* d_ws,
                              size_t ws_size, hipStream_t stream)
{
    const float* x    = (const float*)d_in[0];
    const float* wq   = (const float*)d_in[1];
    const float* bq   = (const float*)d_in[2];
    const float* wk   = (const float*)d_in[3];
    const float* bk   = (const float*)d_in[4];
    const float* wv   = (const float*)d_in[5];
    const float* bv   = (const float*)d_in[6];
    const float* relh = (const float*)d_in[7];
    const float* relw = (const float*)d_in[8];
    const float* reld = (const float*)d_in[9];

    u16*   kws   = (u16*)d_ws;                         // (NVOX+1)*128 bf16
    u16*   vws   = kws + (size_t)(NVOX + 1) * CCH;     // (NVOX+1)*128 bf16
    float* biasW = (float*)(vws + (size_t)(NVOX + 1) * CCH);  // 27 fp32

    dim3 pgrid(NVOX / 64, 3);
    proj_kernel<<<pgrid, 256, 0, stream>>>(x, wq, bq, wk, bk, wv, bv,
                                           relh, relw, reld,
                                           (float*)d_out, kws, vws, biasW);
    attn_kernel<<<NVOX / 16, 256, 0, stream>>>((float*)d_out, kws, vws, biasW);
}